// Round 9
// baseline (335.910 us; speedup 1.0000x reference)
//
#include <hip/hip_runtime.h>
#include <stdint.h>

typedef _Float16 f16x8 __attribute__((ext_vector_type(8)));
typedef float floatx4 __attribute__((ext_vector_type(4)));
typedef unsigned int u32x4 __attribute__((ext_vector_type(4)));

#define RR 147456   // 384*384 rows
#define NC 128      // channels
#define NN 384
// chunk-interleaved layout for at/bt/gate/o16:
//   addr(pos, c) = (pos>>6)*8192 + c*64 + (pos&63)   [fp16 units]

__device__ inline floatx4 zero4() { floatx4 v; v[0]=0.f; v[1]=0.f; v[2]=0.f; v[3]=0.f; return v; }
__device__ inline float sigmoidf_(float x) { return 1.f / (1.f + __expf(-x)); }

// ---------------------------------------------------------------------------
// k0: repack six fp32 128x128 weights into fp16 FRAGMENT-MAJOR order (as r5).
// ---------------------------------------------------------------------------
__global__ __launch_bounds__(256) void k0_wt(
    const float* __restrict__ w0, const float* __restrict__ w1,
    const float* __restrict__ w2, const float* __restrict__ w3,
    const float* __restrict__ w4, const float* __restrict__ w5,
    _Float16* __restrict__ wf)
{
  const float* w;
  switch (blockIdx.x) {
    case 0: w = w0; break; case 1: w = w1; break; case 2: w = w2; break;
    case 3: w = w3; break; case 4: w = w4; break; default: w = w5; break;
  }
  _Float16* out = wf + blockIdx.x * 16384;
  const int t = threadIdx.x;
  for (int it = 0; it < 64; ++it) {
    int f = it * 256 + t;
    int j  = f & 7;
    int ln = (f >> 3) & 63;
    int nt = (f >> 9) & 7;
    int k0 = f >> 12;
    int k = k0 * 32 + (ln >> 4) * 8 + j;
    int n = nt * 16 + (ln & 15);
    out[f] = (_Float16)w[k * 128 + n];
  }
}

// ---------------------------------------------------------------------------
// k2: LN1 -> 5 N-split GEMMs -> LDS bounce -> NONTEMPORAL contiguous stores.
// NT streams avoid L2 dirty-line residency (round-5/6/8 counters showed
// ~1.7x write amplification whenever occupancy was high; round-3 low-occ
// run wrote exactly once). Everything else as round 8.
// ---------------------------------------------------------------------------
__global__ __launch_bounds__(256, 4) void k2_ln_gemm(
    const float* __restrict__ z, const float* __restrict__ ln1g, const float* __restrict__ ln1b,
    const _Float16* __restrict__ wf,
    const float* __restrict__ ba, const float* __restrict__ bga,
    const float* __restrict__ bb, const float* __restrict__ bgb,
    const float* __restrict__ bg,
    _Float16* __restrict__ at, _Float16* __restrict__ bt, _Float16* __restrict__ gate)
{
  __shared__ __align__(16) _Float16 zns[64][136];    // zn tile, padded stride
  __shared__ __align__(16) _Float16 bnc[4][32 * 72]; // per-wave store bounce
  const int t = threadIdx.x;
  const int w = t >> 6, lane = t & 63;
  const int l15 = lane & 15, quad = lane >> 4;
  const int r0 = blockIdx.x * 64;
  const int nt0 = w * 2;

  // ---- LN1 (16-lane-group reduce)
  {
    const int g = lane >> 4, h = lane & 15;
    float4 ga = *(const float4*)(ln1g + h*8);
    float4 gb = *(const float4*)(ln1g + h*8 + 4);
    float4 bba = *(const float4*)(ln1b + h*8);
    float4 bbb = *(const float4*)(ln1b + h*8 + 4);
    #pragma unroll
    for (int rr = 0; rr < 4; ++rr) {
      int row = w * 16 + rr * 4 + g;
      const float* zp = z + (size_t)(r0 + row) * NC + h * 8;
      float4 xa = *(const float4*)zp;
      float4 xb = *(const float4*)(zp + 4);
      float s = xa.x + xa.y + xa.z + xa.w + xb.x + xb.y + xb.z + xb.w;
      float q = xa.x*xa.x + xa.y*xa.y + xa.z*xa.z + xa.w*xa.w
              + xb.x*xb.x + xb.y*xb.y + xb.z*xb.z + xb.w*xb.w;
      #pragma unroll
      for (int m = 1; m < 16; m <<= 1) { s += __shfl_xor(s, m); q += __shfl_xor(q, m); }
      float mean = s * (1.f/128.f);
      float var  = q * (1.f/128.f) - mean*mean;
      float rs = rsqrtf(var + 1e-5f);
      union { uint4 u; _Float16 hh[8]; } pk;
      pk.hh[0] = (_Float16)((xa.x - mean) * rs * ga.x + bba.x);
      pk.hh[1] = (_Float16)((xa.y - mean) * rs * ga.y + bba.y);
      pk.hh[2] = (_Float16)((xa.z - mean) * rs * ga.z + bba.z);
      pk.hh[3] = (_Float16)((xa.w - mean) * rs * ga.w + bba.w);
      pk.hh[4] = (_Float16)((xb.x - mean) * rs * gb.x + bbb.x);
      pk.hh[5] = (_Float16)((xb.y - mean) * rs * gb.y + bbb.y);
      pk.hh[6] = (_Float16)((xb.z - mean) * rs * gb.z + bbb.z);
      pk.hh[7] = (_Float16)((xb.w - mean) * rs * gb.w + bbb.w);
      *(uint4*)&zns[row][h * 8] = pk.u;
    }
  }
  __syncthreads();

  const _Float16* pw = wf + lane * 8;
  f16x8 bw[4][2];
  floatx4 acc[4][2];
  union PkU { unsigned int u; _Float16 h[2]; };
  PkU sig[4][2][2];

  auto loadw = [&](int slot) {
    const _Float16* p = pw + slot * 16384;
    #pragma unroll
    for (int k0 = 0; k0 < 4; ++k0)
      #pragma unroll
      for (int j = 0; j < 2; ++j)
        bw[k0][j] = *(const f16x8*)(p + (k0*8 + nt0 + j) * 512);
  };
  auto dogemm = [&]() {
    #pragma unroll
    for (int mt = 0; mt < 4; ++mt) {
      acc[mt][0] = zero4(); acc[mt][1] = zero4();
      #pragma unroll
      for (int k0 = 0; k0 < 4; ++k0) {
        f16x8 af = *(const f16x8*)&zns[mt*16 + l15][k0*32 + quad*8];
        acc[mt][0] = __builtin_amdgcn_mfma_f32_16x16x32_f16(af, bw[k0][0], acc[mt][0], 0, 0, 0);
        acc[mt][1] = __builtin_amdgcn_mfma_f32_16x16x32_f16(af, bw[k0][1], acc[mt][1], 0, 0, 0);
      }
    }
  };
  auto sigpack = [&](const float* big) {
    #pragma unroll
    for (int j = 0; j < 2; ++j) {
      float bgv = big[(nt0 + j)*16 + l15];
      #pragma unroll
      for (int mt = 0; mt < 4; ++mt) {
        sig[mt][j][0].h[0] = (_Float16)sigmoidf_(acc[mt][j][0] + bgv);
        sig[mt][j][0].h[1] = (_Float16)sigmoidf_(acc[mt][j][1] + bgv);
        sig[mt][j][1].h[0] = (_Float16)sigmoidf_(acc[mt][j][2] + bgv);
        sig[mt][j][1].h[1] = (_Float16)sigmoidf_(acc[mt][j][3] + bgv);
      }
    }
  };
  // drain wave's bounce tile: contiguous 4KB per wave, NONTEMPORAL
  auto bounce_out = [&](_Float16* dst) {
    asm volatile("s_waitcnt lgkmcnt(0)" ::: "memory");
    _Float16* base = dst + (size_t)blockIdx.x * 8192 + w * 2048;
    #pragma unroll
    for (int i = 0; i < 4; ++i) {
      int f = i * 512 + lane * 8;          // f = cp*64 + pos
      int cp = f >> 6, pos = f & 63;
      u32x4 v = *(const u32x4*)&bnc[w][cp * 72 + pos];
      __builtin_nontemporal_store(v, (u32x4*)(base + f));
    }
  };
  auto combine_store = [&](const float* bia, _Float16* dst) {
    #pragma unroll
    for (int j = 0; j < 2; ++j) {
      int c = (nt0 + j)*16 + l15;
      float bav = bia[c];
      #pragma unroll
      for (int mt = 0; mt < 4; ++mt) {
        union { uint2 u2; _Float16 h[4]; } pk;
        pk.h[0] = (_Float16)((acc[mt][j][0] + bav) * (float)sig[mt][j][0].h[0]);
        pk.h[1] = (_Float16)((acc[mt][j][1] + bav) * (float)sig[mt][j][0].h[1]);
        pk.h[2] = (_Float16)((acc[mt][j][2] + bav) * (float)sig[mt][j][1].h[0]);
        pk.h[3] = (_Float16)((acc[mt][j][3] + bav) * (float)sig[mt][j][1].h[1]);
        *(uint2*)&bnc[w][(j*16 + l15) * 72 + mt*16 + quad*4] = pk.u2;
      }
    }
    bounce_out(dst);
  };

  loadw(1); dogemm(); sigpack(bga);
  loadw(0); dogemm();
  loadw(3);
  combine_store(ba, at);
  dogemm(); sigpack(bgb);
  loadw(2); dogemm();
  loadw(4);
  combine_store(bb, bt);
  dogemm();
  #pragma unroll
  for (int j = 0; j < 2; ++j) {
    float bgv = bg[(nt0 + j)*16 + l15];
    #pragma unroll
    for (int mt = 0; mt < 4; ++mt) {
      union { uint2 u2; _Float16 h[4]; } pk;
      #pragma unroll
      for (int r = 0; r < 4; ++r)
        pk.h[r] = (_Float16)sigmoidf_(acc[mt][j][r] + bgv);
      *(uint2*)&bnc[w][(j*16 + l15) * 72 + mt*16 + quad*4] = pk.u2;
    }
  }
  bounce_out(gate);
}

// ---------------------------------------------------------------------------
// k3 v2: 128-thread blocks, 2 waves, wave tile 64x128.
// Per K-step(32) per wave: 12 ds_read_b128 (~144cy) vs 32 MFMA (~154cy) —
// balanced, 2x better LDS:MFMA ratio than the old 64x64 wave tile.
// Load-early/write-late single-reg-set pipeline, ONE barrier per K-step.
// ---------------------------------------------------------------------------
__global__ __launch_bounds__(128, 2) void k3_tri(
    const _Float16* __restrict__ at, const _Float16* __restrict__ bt, _Float16* __restrict__ o)
{
  __shared__ __align__(16) _Float16 As[2][128 * 40];
  __shared__ __align__(16) _Float16 Bs[2][128 * 40];
  const int t = threadIdx.x;
  const int w = t >> 6, lane = t & 63, l15 = lane & 15, quad = lane >> 4;
  const int c = blockIdx.y;
  const int i0 = (blockIdx.x / 3) * 128, j0 = (blockIdx.x % 3) * 128;

  // staging: thread covers rows {s2*32 + (t>>2)}, k-offset (t&3)*8 (16B each)
  const int sj = (t & 3) * 8, sr = t >> 2;
  f16x8 aS[4], bS[4];

  auto gload = [&](int kk) {
    size_t ko = ((size_t)(kk >> 6)) * 8192 + (size_t)((kk & 63) + sj) + (size_t)c * 64;
    #pragma unroll
    for (int s2 = 0; s2 < 4; ++s2) {
      int row = s2 * 32 + sr;
      aS[s2] = *(const f16x8*)(at + (size_t)(i0 + row) * 6 * 8192 + ko);
      bS[s2] = *(const f16x8*)(bt + (size_t)(j0 + row) * 6 * 8192 + ko);
    }
  };
  auto swrite = [&](int buf) {
    #pragma unroll
    for (int s2 = 0; s2 < 4; ++s2) {
      int row = s2 * 32 + sr;
      *(f16x8*)&As[buf][row * 40 + sj] = aS[s2];
      *(f16x8*)&Bs[buf][row * 40 + sj] = bS[s2];
    }
  };

  floatx4 acc[4][8];
  #pragma unroll
  for (int mt = 0; mt < 4; ++mt)
    #pragma unroll
    for (int nt = 0; nt < 8; ++nt) acc[mt][nt] = zero4();

  auto compute = [&](int buf) {
    f16x8 af[4], bfr[8];
    #pragma unroll
    for (int mt = 0; mt < 4; ++mt)
      af[mt] = *(const f16x8*)&As[buf][(w*64 + mt*16 + l15) * 40 + quad*8];
    #pragma unroll
    for (int nt = 0; nt < 8; ++nt)
      bfr[nt] = *(const f16x8*)&Bs[buf][(nt*16 + l15) * 40 + quad*8];
    #pragma unroll
    for (int mt = 0; mt < 4; ++mt)
      #pragma unroll
      for (int nt = 0; nt < 8; ++nt)
        acc[mt][nt] = __builtin_amdgcn_mfma_f32_16x16x32_f16(af[mt], bfr[nt], acc[mt][nt], 0, 0, 0);
  };

  // 12 K-steps of 32; step s computes buf s&1.
  gload(0); swrite(0); __syncthreads();
  for (int s = 0; s < 12; ++s) {
    if (s + 1 < 12) gload((s + 1) * 32);       // in flight during compute
    compute(s & 1);
    if (s + 1 < 12) { swrite((s + 1) & 1); __syncthreads(); }
  }

  // store o16 chunk layout, NONTEMPORAL
  #pragma unroll
  for (int mt = 0; mt < 4; ++mt) {
    #pragma unroll
    for (int r = 0; r < 4; ++r) {
      int i = i0 + w*64 + mt*16 + quad*4 + r;
      _Float16* ob = o + (size_t)(i*6 + (j0 >> 6)) * 8192 + (size_t)c * 64;
      #pragma unroll
      for (int nt = 0; nt < 8; ++nt) {
        _Float16* p = ob + (size_t)(nt >> 2) * 8192 + (nt & 3)*16 + l15;
        __builtin_nontemporal_store((_Float16)acc[mt][nt][r], p);
      }
    }
  }
}

// ---------------------------------------------------------------------------
// k4: gather o16 chunk -> LDS transpose -> LN2 in place -> N-split MFMA
// with Wo from L2 -> *gate -> fp32 out (NONTEMPORAL: out is never re-read).
// ---------------------------------------------------------------------------
__global__ __launch_bounds__(256, 4) void k4_out(
    const _Float16* __restrict__ o, const _Float16* __restrict__ gate,
    const float* __restrict__ ln2g, const float* __restrict__ ln2b,
    const _Float16* __restrict__ wo5, const float* __restrict__ bo,
    float* __restrict__ out)
{
  __shared__ __align__(16) _Float16 osb[64][136];
  const int t = threadIdx.x;
  const int w = t >> 6, lane = t & 63, l15 = lane & 15, quad = lane >> 4;
  const int r0 = blockIdx.x * 64;
  const int nt0 = w * 2;

  {
    const _Float16* ob = o + (size_t)blockIdx.x * 8192;
    #pragma unroll
    for (int it = 0; it < 4; ++it) {
      int f = (it * 256 + t) * 8;
      int cx = f >> 6, p = f & 63;
      f16x8 v = *(const f16x8*)(ob + f);
      #pragma unroll
      for (int i = 0; i < 8; ++i) osb[p + i][cx] = v[i];
    }
  }
  __syncthreads();

  {
    const int g = lane >> 4, h = lane & 15;
    float4 ga = *(const float4*)(ln2g + h*8);
    float4 gb = *(const float4*)(ln2g + h*8 + 4);
    float4 bba = *(const float4*)(ln2b + h*8);
    float4 bbb = *(const float4*)(ln2b + h*8 + 4);
    #pragma unroll
    for (int rr = 0; rr < 4; ++rr) {
      int row = w * 16 + rr * 4 + g;
      f16x8 xv = *(const f16x8*)&osb[row][h*8];
      float x0 = (float)xv[0], x1 = (float)xv[1], x2 = (float)xv[2], x3 = (float)xv[3];
      float x4 = (float)xv[4], x5 = (float)xv[5], x6 = (float)xv[6], x7 = (float)xv[7];
      float s = x0+x1+x2+x3+x4+x5+x6+x7;
      float q = x0*x0+x1*x1+x2*x2+x3*x3+x4*x4+x5*x5+x6*x6+x7*x7;
      #pragma unroll
      for (int m = 1; m < 16; m <<= 1) { s += __shfl_xor(s, m); q += __shfl_xor(q, m); }
      float mean = s * (1.f/128.f);
      float var  = q * (1.f/128.f) - mean*mean;
      float rs = rsqrtf(var + 1e-5f);
      union { uint4 u; _Float16 hh[8]; } pk;
      pk.hh[0] = (_Float16)((x0 - mean) * rs * ga.x + bba.x);
      pk.hh[1] = (_Float16)((x1 - mean) * rs * ga.y + bba.y);
      pk.hh[2] = (_Float16)((x2 - mean) * rs * ga.z + bba.z);
      pk.hh[3] = (_Float16)((x3 - mean) * rs * ga.w + bba.w);
      pk.hh[4] = (_Float16)((x4 - mean) * rs * gb.x + bbb.x);
      pk.hh[5] = (_Float16)((x5 - mean) * rs * gb.y + bbb.y);
      pk.hh[6] = (_Float16)((x6 - mean) * rs * gb.z + bbb.z);
      pk.hh[7] = (_Float16)((x7 - mean) * rs * gb.w + bbb.w);
      *(uint4*)&osb[row][h * 8] = pk.u;
    }
  }
  __syncthreads();

  f16x8 bw[4][2];
  {
    const _Float16* p = wo5 + lane * 8;
    #pragma unroll
    for (int k0 = 0; k0 < 4; ++k0)
      #pragma unroll
      for (int j = 0; j < 2; ++j)
        bw[k0][j] = *(const f16x8*)(p + (k0*8 + nt0 + j) * 512);
  }
  floatx4 acc[4][2];
  #pragma unroll
  for (int mt = 0; mt < 4; ++mt) {
    acc[mt][0] = zero4(); acc[mt][1] = zero4();
    #pragma unroll
    for (int k0 = 0; k0 < 4; ++k0) {
      f16x8 af = *(const f16x8*)&osb[mt*16 + l15][k0*32 + quad*8];
      acc[mt][0] = __builtin_amdgcn_mfma_f32_16x16x32_f16(af, bw[k0][0], acc[mt][0], 0, 0, 0);
      acc[mt][1] = __builtin_amdgcn_mfma_f32_16x16x32_f16(af, bw[k0][1], acc[mt][1], 0, 0, 0);
    }
  }

  #pragma unroll
  for (int j = 0; j < 2; ++j) {
    int cch = (nt0 + j)*16 + l15;
    float bov = bo[cch];
    #pragma unroll
    for (int mt = 0; mt < 4; ++mt) {
      union { uint2 u2; _Float16 h[4]; } gk;
      gk.u2 = *(const uint2*)(gate + (size_t)blockIdx.x * 8192 + (size_t)cch * 64 + mt*16 + quad*4);
      #pragma unroll
      for (int r = 0; r < 4; ++r) {
        int rl = mt*16 + quad*4 + r;
        __builtin_nontemporal_store((float)gk.h[r] * (acc[mt][j][r] + bov),
                                    out + (size_t)(r0 + rl) * NC + cch);
      }
    }
  }
}

// ---------------------------------------------------------------------------
// Workspace layout (bytes): as round 8 (all chunk-layout fp16 + wf).
// ---------------------------------------------------------------------------
extern "C" void kernel_launch(void* const* d_in, const int* in_sizes, int n_in,
                              void* d_out, int out_size, void* d_ws, size_t ws_size,
                              hipStream_t stream) {
  const float* z    = (const float*)d_in[0];
  const float* l1g  = (const float*)d_in[1];
  const float* l1b  = (const float*)d_in[2];
  const float* l2g  = (const float*)d_in[3];
  const float* l2b  = (const float*)d_in[4];
  const float* Wa   = (const float*)d_in[5];
  const float* ba   = (const float*)d_in[6];
  const float* Wga  = (const float*)d_in[7];
  const float* bga  = (const float*)d_in[8];
  const float* Wb   = (const float*)d_in[9];
  const float* bb   = (const float*)d_in[10];
  const float* Wgb  = (const float*)d_in[11];
  const float* bgb  = (const float*)d_in[12];
  const float* Wg   = (const float*)d_in[13];
  const float* bg   = (const float*)d_in[14];
  const float* Wo   = (const float*)d_in[15];
  const float* bo   = (const float*)d_in[16];

  char* ws = (char*)d_ws;
  _Float16* at_  = (_Float16*)(ws + 0);
  _Float16* bt_  = (_Float16*)(ws + 37748736);
  _Float16* gate = (_Float16*)(ws + 75497472);
  _Float16* o16  = (_Float16*)(ws + 113246208);
  _Float16* wf   = (_Float16*)(ws + 188743680);

  hipLaunchKernelGGL(k0_wt, dim3(6), dim3(256), 0, stream, Wa, Wga, Wb, Wgb, Wg, Wo, wf);
  hipLaunchKernelGGL(k2_ln_gemm, dim3(2304), dim3(256), 0, stream,
                     z, l1g, l1b, wf, ba, bga, bb, bgb, bg, at_, bt_, gate);
  hipLaunchKernelGGL(k3_tri, dim3(9, 128), dim3(128), 0, stream, at_, bt_, o16);
  hipLaunchKernelGGL(k4_out, dim3(2304), dim3(256), 0, stream,
                     o16, gate, l2g, l2b, wf + 5*16384, bo, (float*)d_out);
}

// Round 11
// 310.379 us; speedup vs baseline: 1.0823x; 1.0823x over previous
//
#include <hip/hip_runtime.h>
#include <stdint.h>

typedef _Float16 f16x8 __attribute__((ext_vector_type(8)));
typedef float floatx4 __attribute__((ext_vector_type(4)));
typedef unsigned int u32x4 __attribute__((ext_vector_type(4)));

#define RR 147456   // 384*384 rows
#define NC 128      // channels
#define NN 384
// chunk-interleaved layout for at/bt/gate/o16:
//   addr(pos, c) = (pos>>6)*8192 + c*64 + (pos&63)   [fp16 units]

__device__ inline floatx4 zero4() { floatx4 v; v[0]=0.f; v[1]=0.f; v[2]=0.f; v[3]=0.f; return v; }
__device__ inline float sigmoidf_(float x) { return 1.f / (1.f + __expf(-x)); }

// ---------------------------------------------------------------------------
// k0: repack six fp32 128x128 weights into fp16 FRAGMENT-MAJOR order (as r5).
// ---------------------------------------------------------------------------
__global__ __launch_bounds__(256) void k0_wt(
    const float* __restrict__ w0, const float* __restrict__ w1,
    const float* __restrict__ w2, const float* __restrict__ w3,
    const float* __restrict__ w4, const float* __restrict__ w5,
    _Float16* __restrict__ wf)
{
  const float* w;
  switch (blockIdx.x) {
    case 0: w = w0; break; case 1: w = w1; break; case 2: w = w2; break;
    case 3: w = w3; break; case 4: w = w4; break; default: w = w5; break;
  }
  _Float16* out = wf + blockIdx.x * 16384;
  const int t = threadIdx.x;
  for (int it = 0; it < 64; ++it) {
    int f = it * 256 + t;
    int j  = f & 7;
    int ln = (f >> 3) & 63;
    int nt = (f >> 9) & 7;
    int k0 = f >> 12;
    int k = k0 * 32 + (ln >> 4) * 8 + j;
    int n = nt * 16 + (ln & 15);
    out[f] = (_Float16)w[k * 128 + n];
  }
}

// ---------------------------------------------------------------------------
// k2: LN1 -> 5 N-split GEMMs. TWO weight buffers so every weight load is
// issued >=1 full GEMM before its consumer (r9 had 3 of 5 loads at zero
// distance -> each GEMM ate a full L2 round-trip; k2 was latency-bound:
// 1.9 TB/s real traffic, MfmaUtil 9.7%, nothing saturated).
// ---------------------------------------------------------------------------
__global__ __launch_bounds__(256, 3) void k2_ln_gemm(
    const float* __restrict__ z, const float* __restrict__ ln1g, const float* __restrict__ ln1b,
    const _Float16* __restrict__ wf,
    const float* __restrict__ ba, const float* __restrict__ bga,
    const float* __restrict__ bb, const float* __restrict__ bgb,
    const float* __restrict__ bg,
    _Float16* __restrict__ at, _Float16* __restrict__ bt, _Float16* __restrict__ gate)
{
  __shared__ __align__(16) _Float16 zns[64][136];    // zn tile, padded stride
  __shared__ __align__(16) _Float16 bnc[4][32 * 72]; // per-wave store bounce
  const int t = threadIdx.x;
  const int w = t >> 6, lane = t & 63;
  const int l15 = lane & 15, quad = lane >> 4;
  const int r0 = blockIdx.x * 64;
  const int nt0 = w * 2;

  // ---- LN1 (16-lane-group reduce)
  {
    const int g = lane >> 4, h = lane & 15;
    float4 ga = *(const float4*)(ln1g + h*8);
    float4 gb = *(const float4*)(ln1g + h*8 + 4);
    float4 bba = *(const float4*)(ln1b + h*8);
    float4 bbb = *(const float4*)(ln1b + h*8 + 4);
    #pragma unroll
    for (int rr = 0; rr < 4; ++rr) {
      int row = w * 16 + rr * 4 + g;
      const float* zp = z + (size_t)(r0 + row) * NC + h * 8;
      float4 xa = *(const float4*)zp;
      float4 xb = *(const float4*)(zp + 4);
      float s = xa.x + xa.y + xa.z + xa.w + xb.x + xb.y + xb.z + xb.w;
      float q = xa.x*xa.x + xa.y*xa.y + xa.z*xa.z + xa.w*xa.w
              + xb.x*xb.x + xb.y*xb.y + xb.z*xb.z + xb.w*xb.w;
      #pragma unroll
      for (int m = 1; m < 16; m <<= 1) { s += __shfl_xor(s, m); q += __shfl_xor(q, m); }
      float mean = s * (1.f/128.f);
      float var  = q * (1.f/128.f) - mean*mean;
      float rs = rsqrtf(var + 1e-5f);
      union { uint4 u; _Float16 hh[8]; } pk;
      pk.hh[0] = (_Float16)((xa.x - mean) * rs * ga.x + bba.x);
      pk.hh[1] = (_Float16)((xa.y - mean) * rs * ga.y + bba.y);
      pk.hh[2] = (_Float16)((xa.z - mean) * rs * ga.z + bba.z);
      pk.hh[3] = (_Float16)((xa.w - mean) * rs * ga.w + bba.w);
      pk.hh[4] = (_Float16)((xb.x - mean) * rs * gb.x + bbb.x);
      pk.hh[5] = (_Float16)((xb.y - mean) * rs * gb.y + bbb.y);
      pk.hh[6] = (_Float16)((xb.z - mean) * rs * gb.z + bbb.z);
      pk.hh[7] = (_Float16)((xb.w - mean) * rs * gb.w + bbb.w);
      *(uint4*)&zns[row][h * 8] = pk.u;
    }
  }
  __syncthreads();

  const _Float16* pw = wf + lane * 8;
  f16x8 bwA[4][2], bwB[4][2];       // double-buffered weights
  floatx4 acc[4][2];
  union PkU { unsigned int u; _Float16 h[2]; };
  PkU sig[4][2][2];

  auto loadw = [&](f16x8 (&bw)[4][2], int slot) {
    const _Float16* p = pw + slot * 16384;
    #pragma unroll
    for (int k0 = 0; k0 < 4; ++k0)
      #pragma unroll
      for (int j = 0; j < 2; ++j)
        bw[k0][j] = *(const f16x8*)(p + (k0*8 + nt0 + j) * 512);
  };
  auto dogemm = [&](const f16x8 (&bw)[4][2]) {
    #pragma unroll
    for (int mt = 0; mt < 4; ++mt) {
      acc[mt][0] = zero4(); acc[mt][1] = zero4();
      #pragma unroll
      for (int k0 = 0; k0 < 4; ++k0) {
        f16x8 af = *(const f16x8*)&zns[mt*16 + l15][k0*32 + quad*8];
        acc[mt][0] = __builtin_amdgcn_mfma_f32_16x16x32_f16(af, bw[k0][0], acc[mt][0], 0, 0, 0);
        acc[mt][1] = __builtin_amdgcn_mfma_f32_16x16x32_f16(af, bw[k0][1], acc[mt][1], 0, 0, 0);
      }
    }
  };
  auto sigpack = [&](const float* big) {
    #pragma unroll
    for (int j = 0; j < 2; ++j) {
      float bgv = big[(nt0 + j)*16 + l15];
      #pragma unroll
      for (int mt = 0; mt < 4; ++mt) {
        sig[mt][j][0].h[0] = (_Float16)sigmoidf_(acc[mt][j][0] + bgv);
        sig[mt][j][0].h[1] = (_Float16)sigmoidf_(acc[mt][j][1] + bgv);
        sig[mt][j][1].h[0] = (_Float16)sigmoidf_(acc[mt][j][2] + bgv);
        sig[mt][j][1].h[1] = (_Float16)sigmoidf_(acc[mt][j][3] + bgv);
      }
    }
  };
  auto bounce_out = [&](_Float16* dst) {
    asm volatile("s_waitcnt lgkmcnt(0)" ::: "memory");
    _Float16* base = dst + (size_t)blockIdx.x * 8192 + w * 2048;
    #pragma unroll
    for (int i = 0; i < 4; ++i) {
      int f = i * 512 + lane * 8;
      int cp = f >> 6, pos = f & 63;
      u32x4 v = *(const u32x4*)&bnc[w][cp * 72 + pos];
      __builtin_nontemporal_store(v, (u32x4*)(base + f));
    }
  };
  auto combine_store = [&](const float* bia, _Float16* dst) {
    #pragma unroll
    for (int j = 0; j < 2; ++j) {
      int c = (nt0 + j)*16 + l15;
      float bav = bia[c];
      #pragma unroll
      for (int mt = 0; mt < 4; ++mt) {
        union { uint2 u2; _Float16 h[4]; } pk;
        pk.h[0] = (_Float16)((acc[mt][j][0] + bav) * (float)sig[mt][j][0].h[0]);
        pk.h[1] = (_Float16)((acc[mt][j][1] + bav) * (float)sig[mt][j][0].h[1]);
        pk.h[2] = (_Float16)((acc[mt][j][2] + bav) * (float)sig[mt][j][1].h[0]);
        pk.h[3] = (_Float16)((acc[mt][j][3] + bav) * (float)sig[mt][j][1].h[1]);
        *(uint2*)&bnc[w][(j*16 + l15) * 72 + mt*16 + quad*4] = pk.u2;
      }
    }
    bounce_out(dst);
  };

  // schedule: every loadw >=1 GEMM ahead of its consumer
  loadw(bwA, 1); loadw(bwB, 0);      // Wga, Wa in flight together
  dogemm(bwA); sigpack(bga);         // Wga
  loadw(bwA, 3);                     // Wgb (consumed 2 phases later)
  dogemm(bwB); combine_store(ba, at);// Wa
  loadw(bwB, 2);                     // Wb
  dogemm(bwA); sigpack(bgb);         // Wgb
  loadw(bwA, 4);                     // Wg
  dogemm(bwB); combine_store(bb, bt);// Wb
  dogemm(bwA);                       // Wg
  #pragma unroll
  for (int j = 0; j < 2; ++j) {
    float bgv = bg[(nt0 + j)*16 + l15];
    #pragma unroll
    for (int mt = 0; mt < 4; ++mt) {
      union { uint2 u2; _Float16 h[4]; } pk;
      #pragma unroll
      for (int r = 0; r < 4; ++r)
        pk.h[r] = (_Float16)sigmoidf_(acc[mt][j][r] + bgv);
      *(uint2*)&bnc[w][(j*16 + l15) * 72 + mt*16 + quad*4] = pk.u2;
    }
  }
  bounce_out(gate);
}

// ---------------------------------------------------------------------------
// k3: triangle einsum, r9 pipeline + XCD-locality swizzle: 1D grid,
// xcd = b&7 gets all 9 tiles of the 16 channels with c%8==xcd, channel-major
// order -> a channel's A+B panels (576KB) stay hot in that XCD's 4MB L2, so
// the 3x panel re-read hits L2 (~200cy) instead of L3/HBM (600+cy), which
// the existing 1-step-ahead pipeline CAN hide.
// ---------------------------------------------------------------------------
__global__ __launch_bounds__(128, 2) void k3_tri(
    const _Float16* __restrict__ at, const _Float16* __restrict__ bt, _Float16* __restrict__ o)
{
  __shared__ __align__(16) _Float16 As[2][128 * 40];
  __shared__ __align__(16) _Float16 Bs[2][128 * 40];
  const int t = threadIdx.x;
  const int w = t >> 6, lane = t & 63, l15 = lane & 15, quad = lane >> 4;

  // XCD swizzle: b -> (xcd = b&7, k = b>>3); c = xcd + 8*(k/9); tile = k%9
  const int b = blockIdx.x;
  const int xcd = b & 7, kk9 = b >> 3;
  const int c = xcd + 8 * (kk9 / 9);
  const int tile = kk9 % 9;
  const int i0 = (tile / 3) * 128, j0 = (tile % 3) * 128;

  const int sj = (t & 3) * 8, sr = t >> 2;
  f16x8 aS[4], bS[4];

  auto gload = [&](int kk) {
    size_t ko = ((size_t)(kk >> 6)) * 8192 + (size_t)((kk & 63) + sj) + (size_t)c * 64;
    #pragma unroll
    for (int s2 = 0; s2 < 4; ++s2) {
      int row = s2 * 32 + sr;
      aS[s2] = *(const f16x8*)(at + (size_t)(i0 + row) * 6 * 8192 + ko);
      bS[s2] = *(const f16x8*)(bt + (size_t)(j0 + row) * 6 * 8192 + ko);
    }
  };
  auto swrite = [&](int buf) {
    #pragma unroll
    for (int s2 = 0; s2 < 4; ++s2) {
      int row = s2 * 32 + sr;
      *(f16x8*)&As[buf][row * 40 + sj] = aS[s2];
      *(f16x8*)&Bs[buf][row * 40 + sj] = bS[s2];
    }
  };

  floatx4 acc[4][8];
  #pragma unroll
  for (int mt = 0; mt < 4; ++mt)
    #pragma unroll
    for (int nt = 0; nt < 8; ++nt) acc[mt][nt] = zero4();

  auto compute = [&](int buf) {
    f16x8 af[4], bfr[8];
    #pragma unroll
    for (int mt = 0; mt < 4; ++mt)
      af[mt] = *(const f16x8*)&As[buf][(w*64 + mt*16 + l15) * 40 + quad*8];
    #pragma unroll
    for (int nt = 0; nt < 8; ++nt)
      bfr[nt] = *(const f16x8*)&Bs[buf][(nt*16 + l15) * 40 + quad*8];
    #pragma unroll
    for (int mt = 0; mt < 4; ++mt)
      #pragma unroll
      for (int nt = 0; nt < 8; ++nt)
        acc[mt][nt] = __builtin_amdgcn_mfma_f32_16x16x32_f16(af[mt], bfr[nt], acc[mt][nt], 0, 0, 0);
  };

  gload(0); swrite(0); __syncthreads();
  for (int s = 0; s < 12; ++s) {
    if (s + 1 < 12) gload((s + 1) * 32);
    compute(s & 1);
    if (s + 1 < 12) { swrite((s + 1) & 1); __syncthreads(); }
  }

  // store o16 chunk layout, NONTEMPORAL
  #pragma unroll
  for (int mt = 0; mt < 4; ++mt) {
    #pragma unroll
    for (int r = 0; r < 4; ++r) {
      int i = i0 + w*64 + mt*16 + quad*4 + r;
      _Float16* ob = o + (size_t)(i*6 + (j0 >> 6)) * 8192 + (size_t)c * 64;
      #pragma unroll
      for (int nt = 0; nt < 8; ++nt) {
        _Float16* p = ob + (size_t)(nt >> 2) * 8192 + (nt & 3)*16 + l15;
        __builtin_nontemporal_store((_Float16)acc[mt][nt][r], p);
      }
    }
  }
}

// ---------------------------------------------------------------------------
// k4: Wo-fragment and gate loads hoisted to the TOP (independent of the o16
// pipeline) so the post-LN2 tail has zero cold loads. Rest as r9.
// ---------------------------------------------------------------------------
__global__ __launch_bounds__(256, 4) void k4_out(
    const _Float16* __restrict__ o, const _Float16* __restrict__ gate,
    const float* __restrict__ ln2g, const float* __restrict__ ln2b,
    const _Float16* __restrict__ wo5, const float* __restrict__ bo,
    float* __restrict__ out)
{
  __shared__ __align__(16) _Float16 osb[64][136];
  const int t = threadIdx.x;
  const int w = t >> 6, lane = t & 63, l15 = lane & 15, quad = lane >> 4;
  const int r0 = blockIdx.x * 64;
  const int nt0 = w * 2;

  // hoisted: weights + gate (both independent of o16)
  f16x8 bw[4][2];
  {
    const _Float16* p = wo5 + lane * 8;
    #pragma unroll
    for (int k0 = 0; k0 < 4; ++k0)
      #pragma unroll
      for (int j = 0; j < 2; ++j)
        bw[k0][j] = *(const f16x8*)(p + (k0*8 + nt0 + j) * 512);
  }
  union GkU { uint2 u2; _Float16 h[4]; };
  GkU gk[2][4];
  #pragma unroll
  for (int j = 0; j < 2; ++j) {
    int cch = (nt0 + j)*16 + l15;
    #pragma unroll
    for (int mt = 0; mt < 4; ++mt)
      gk[j][mt].u2 = *(const uint2*)(gate + (size_t)blockIdx.x * 8192 + (size_t)cch * 64 + mt*16 + quad*4);
  }

  // gather o16 chunk -> LDS transpose
  {
    const _Float16* ob = o + (size_t)blockIdx.x * 8192;
    #pragma unroll
    for (int it = 0; it < 4; ++it) {
      int f = (it * 256 + t) * 8;
      int cx = f >> 6, p = f & 63;
      f16x8 v = *(const f16x8*)(ob + f);
      #pragma unroll
      for (int i = 0; i < 8; ++i) osb[p + i][cx] = v[i];
    }
  }
  __syncthreads();

  // LN2 in place
  {
    const int g = lane >> 4, h = lane & 15;
    float4 ga = *(const float4*)(ln2g + h*8);
    float4 gb = *(const float4*)(ln2g + h*8 + 4);
    float4 bba = *(const float4*)(ln2b + h*8);
    float4 bbb = *(const float4*)(ln2b + h*8 + 4);
    #pragma unroll
    for (int rr = 0; rr < 4; ++rr) {
      int row = w * 16 + rr * 4 + g;
      f16x8 xv = *(const f16x8*)&osb[row][h*8];
      float x0 = (float)xv[0], x1 = (float)xv[1], x2 = (float)xv[2], x3 = (float)xv[3];
      float x4 = (float)xv[4], x5 = (float)xv[5], x6 = (float)xv[6], x7 = (float)xv[7];
      float s = x0+x1+x2+x3+x4+x5+x6+x7;
      float q = x0*x0+x1*x1+x2*x2+x3*x3+x4*x4+x5*x5+x6*x6+x7*x7;
      #pragma unroll
      for (int m = 1; m < 16; m <<= 1) { s += __shfl_xor(s, m); q += __shfl_xor(q, m); }
      float mean = s * (1.f/128.f);
      float var  = q * (1.f/128.f) - mean*mean;
      float rs = rsqrtf(var + 1e-5f);
      union { uint4 u; _Float16 hh[8]; } pk;
      pk.hh[0] = (_Float16)((x0 - mean) * rs * ga.x + bba.x);
      pk.hh[1] = (_Float16)((x1 - mean) * rs * ga.y + bba.y);
      pk.hh[2] = (_Float16)((x2 - mean) * rs * ga.z + bba.z);
      pk.hh[3] = (_Float16)((x3 - mean) * rs * ga.w + bba.w);
      pk.hh[4] = (_Float16)((x4 - mean) * rs * gb.x + bbb.x);
      pk.hh[5] = (_Float16)((x5 - mean) * rs * gb.y + bbb.y);
      pk.hh[6] = (_Float16)((x6 - mean) * rs * gb.z + bbb.z);
      pk.hh[7] = (_Float16)((x7 - mean) * rs * gb.w + bbb.w);
      *(uint4*)&osb[row][h * 8] = pk.u;
    }
  }
  __syncthreads();

  floatx4 acc[4][2];
  #pragma unroll
  for (int mt = 0; mt < 4; ++mt) {
    acc[mt][0] = zero4(); acc[mt][1] = zero4();
    #pragma unroll
    for (int k0 = 0; k0 < 4; ++k0) {
      f16x8 af = *(const f16x8*)&osb[mt*16 + l15][k0*32 + quad*8];
      acc[mt][0] = __builtin_amdgcn_mfma_f32_16x16x32_f16(af, bw[k0][0], acc[mt][0], 0, 0, 0);
      acc[mt][1] = __builtin_amdgcn_mfma_f32_16x16x32_f16(af, bw[k0][1], acc[mt][1], 0, 0, 0);
    }
  }

  #pragma unroll
  for (int j = 0; j < 2; ++j) {
    int cch = (nt0 + j)*16 + l15;
    float bov = bo[cch];
    #pragma unroll
    for (int mt = 0; mt < 4; ++mt) {
      #pragma unroll
      for (int r = 0; r < 4; ++r) {
        int rl = mt*16 + quad*4 + r;
        __builtin_nontemporal_store((float)gk[j][mt].h[r] * (acc[mt][j][r] + bov),
                                    out + (size_t)(r0 + rl) * NC + cch);
      }
    }
  }
}

// ---------------------------------------------------------------------------
// Workspace layout (bytes): as round 8 (all chunk-layout fp16 + wf).
// ---------------------------------------------------------------------------
extern "C" void kernel_launch(void* const* d_in, const int* in_sizes, int n_in,
                              void* d_out, int out_size, void* d_ws, size_t ws_size,
                              hipStream_t stream) {
  const float* z    = (const float*)d_in[0];
  const float* l1g  = (const float*)d_in[1];
  const float* l1b  = (const float*)d_in[2];
  const float* l2g  = (const float*)d_in[3];
  const float* l2b  = (const float*)d_in[4];
  const float* Wa   = (const float*)d_in[5];
  const float* ba   = (const float*)d_in[6];
  const float* Wga  = (const float*)d_in[7];
  const float* bga  = (const float*)d_in[8];
  const float* Wb   = (const float*)d_in[9];
  const float* bb   = (const float*)d_in[10];
  const float* Wgb  = (const float*)d_in[11];
  const float* bgb  = (const float*)d_in[12];
  const float* Wg   = (const float*)d_in[13];
  const float* bg   = (const float*)d_in[14];
  const float* Wo   = (const float*)d_in[15];
  const float* bo   = (const float*)d_in[16];

  char* ws = (char*)d_ws;
  _Float16* at_  = (_Float16*)(ws + 0);
  _Float16* bt_  = (_Float16*)(ws + 37748736);
  _Float16* gate = (_Float16*)(ws + 75497472);
  _Float16* o16  = (_Float16*)(ws + 113246208);
  _Float16* wf   = (_Float16*)(ws + 188743680);

  hipLaunchKernelGGL(k0_wt, dim3(6), dim3(256), 0, stream, Wa, Wga, Wb, Wgb, Wg, Wo, wf);
  hipLaunchKernelGGL(k2_ln_gemm, dim3(2304), dim3(256), 0, stream,
                     z, l1g, l1b, wf, ba, bga, bb, bgb, bg, at_, bt_, gate);
  hipLaunchKernelGGL(k3_tri, dim3(1152), dim3(128), 0, stream, at_, bt_, o16);
  hipLaunchKernelGGL(k4_out, dim3(2304), dim3(256), 0, stream,
                     o16, gate, l2g, l2b, wf + 5*16384, bo, (float*)d_out);
}